// Round 7
// baseline (1304.424 us; speedup 1.0000x reference)
//
#include <hip/hip_runtime.h>
#include <hip/hip_cooperative_groups.h>

namespace cg = cooperative_groups;

typedef __bf16 bf16;
typedef __bf16 bf16x8 __attribute__((ext_vector_type(8)));
typedef __bf16 bf16x4 __attribute__((ext_vector_type(4)));
typedef float  f32x4  __attribute__((ext_vector_type(4)));

#define SB 72    // LDS row stride (elems) for 64-wide k tiles
#define CUTOFF -18.0

__device__ __forceinline__ float silu_f(float x){
  float s = 1.f/(1.f+__expf(-x));
  return x*s;
}
__device__ __forceinline__ float silu_bwd_f(float x){
  float s = 1.f/(1.f+__expf(-x));
  float si = x*s;
  return si + s*(1.f-si);
}

// ===================== 64x64 MFMA GEMM job (NT), BK=64, depth-2 prefetch + LDS dbuf =====================
struct MArgs {
  const bf16* A; const bf16* B;
  long sA, sB;
  int lda, ldb;
  int M, N, K;
  int mode;
  float* Cf; long sCf;
  bf16*  Cb; long sCb;               // mode 12: P-tile base (per-batch stride sCb)
  bf16*  Cb2; long sCb2;
  bf16*  Ct;  long sCt;  int ldct;   // transposed output (coalesced via LDS)
  bf16*  Ct2; long sCt2;             // second (scaled) transposed output (mode 3)
  int ldc;
  const float* auxf; int ldax; long sAuxf;
  const bf16*  auxb; long sAuxb;
  const float* rowv; long sRowv;     // mode 1: se2 scale for Ct; mode 3: lr; mode 12: lr[l] (may be null)
  const float* rowv2; long sRowv2;   // mode 3: se1 scale for Ct2
  const double* cd;  long sCd;       // mode 10: dead-K-prefix skip; mode 12: decay factors
  const float* clp;  long sClp;
  bf16* Q; bf16* Ko; float* Vo; const float* bqkv;   // mode 11
};

// modes: 1  Cb=acc, Cb2=silu(acc), Ct=(silu(acc)*rowv[r])^T
//        2  Cb=acc-auxf[r,c], Ct same^T
//        3  v3=silu_bwd(auxb)*acc*rowv[r]; Ct=v3^T, Ct2=(v3*rowv2[r])^T
//        10 Cf=acc+auxf[r,c]*clv  (inputs pre-scaled; dead k-prefix skipped via cd)
//        11 QKV: c<256->Q, <512->Ko (+Ct=Kt), else->Vo (+bias); M spans all batches
//        12 banded-P half tile: P[r][c] = -acc*exp(cd[r]-cd[c])*(c<=r)*(rowv?rowv[c]:1)
// Persistent-block contract: body may use sh[0 .. 2*128*SB) and must end with __syncthreads().
template<int TM>
__device__ __forceinline__ void gemm_body(const MArgs& g, int bm, int bn, int bz, bf16* sh)
{
  constexpr int TTP = 72;                 // transpose-tile stride (elems)
  constexpr int BUF = (TM+64)*SB;
  const int row0 = bm*TM, col0 = bn*64;
  constexpr int NI  = TM/32;
  constexpr int TPR = 256/TM;
  constexpr int EPR = 64/TPR;
  constexpr int NCH = EPR/8;

  const bf16* A = g.A + (long)bz*g.sA;
  const bf16* B = g.B + (long)bz*g.sB;
  const double* cd = g.cd ? g.cd + (long)bz*g.sCd : (const double*)0;
  float* Cf = g.Cf ? g.Cf + (long)bz*g.sCf : (float*)0;
  bf16* Cb  = g.Cb ? g.Cb + (long)bz*g.sCb : (bf16*)0;
  bf16* Cb2 = g.Cb2 ? g.Cb2 + (long)bz*g.sCb2 : (bf16*)0;
  bf16* Ct  = g.Ct ? g.Ct + (long)bz*g.sCt : (bf16*)0;
  bf16* Ct2 = g.Ct2 ? g.Ct2 + (long)bz*g.sCt2 : (bf16*)0;
  const float* auxf = g.auxf ? g.auxf + (long)bz*g.sAuxf : (const float*)0;
  const bf16*  auxb = g.auxb ? g.auxb + (long)bz*g.sAuxb : (const bf16*)0;
  const float* rowv = g.rowv ? g.rowv + (long)bz*g.sRowv : (const float*)0;
  const float* rowv2 = g.rowv2 ? g.rowv2 + (long)bz*g.sRowv2 : (const float*)0;

  const int tid = threadIdx.x;
  const int mode = g.mode;
  const int lane = tid & 63;
  const int w = tid >> 6;
  const int wr = (w >> 1) * (TM/2), wc = (w & 1) * 32;
  const int l15 = lane & 15;
  const int quad = lane >> 4;

  f32x4 acc[NI][2];
  #pragma unroll
  for (int i=0;i<NI;i++)
    #pragma unroll
    for (int j=0;j<2;j++)
      #pragma unroll
      for (int r=0;r<4;r++) acc[i][j][r] = 0.f;

  const int rowA = tid / TPR, kA = (tid % TPR) * EPR;
  const int rowB = tid >> 2,  kB = (tid & 3) * 16;

  // ---- ballot-parallel dead-prefix scan (mode 10 only)
  int klo = 0;
  if (cd && mode == 10) {
    const double cref = cd[g.K-1];
    const int nch = g.K >> 6;
    bool dead = (lane < nch-1) && ((cref - cd[lane*64+63]) < CUTOFF);
    unsigned long long mask = __ballot(dead);
    klo = (int)__builtin_ctzll(~mask) * 64;
  }

  const bf16* Abase = A + (long)(row0+rowA)*g.lda + kA;
  const bf16* Bbase = B + (long)(col0+rowB)*g.ldb + kB;

  // depth-2 prefetch: two named register sets (no runtime indexing -> no scratch)
  bf16x8 paA[NCH], pbA0, pbA1, paB[NCH], pbB0, pbB1;
  #pragma unroll
  for (int p=0;p<NCH;p++) paA[p] = *(const bf16x8*)(Abase + klo + p*8);
  pbA0 = *(const bf16x8*)(Bbase + klo);
  pbA1 = *(const bf16x8*)(Bbase + klo + 8);
  if (klo + 64 < g.K) {
    #pragma unroll
    for (int p=0;p<NCH;p++) paB[p] = *(const bf16x8*)(Abase + klo + 64 + p*8);
    pbB0 = *(const bf16x8*)(Bbase + klo + 64);
    pbB1 = *(const bf16x8*)(Bbase + klo + 64 + 8);
  }

  auto compute = [&](const bf16* As, const bf16* Bs){
    #pragma unroll
    for (int ch=0; ch<2; ch++){
      bf16x8 af[NI], bf2[2];
      #pragma unroll
      for (int i=0;i<NI;i++) af[i]  = *(const bf16x8*)&As[(wr + i*16 + l15)*SB + ch*32 + quad*8];
      #pragma unroll
      for (int j=0;j<2;j++) bf2[j] = *(const bf16x8*)&Bs[(wc + j*16 + l15)*SB + ch*32 + quad*8];
      #pragma unroll
      for (int i=0;i<NI;i++)
        #pragma unroll
        for (int j=0;j<2;j++)
          acc[i][j] = __builtin_amdgcn_mfma_f32_16x16x32_bf16(af[i], bf2[j], acc[i][j], 0, 0, 0);
    }
  };

  for (int k0 = klo; k0 < g.K; k0 += 128) {
    {  // even step: buffer 0, set A
      bf16* As = sh; bf16* Bs = sh + TM*SB;
      #pragma unroll
      for (int p=0;p<NCH;p++) *(bf16x8*)&As[rowA*SB + kA + p*8] = paA[p];
      *(bf16x8*)&Bs[rowB*SB + kB]     = pbA0;
      *(bf16x8*)&Bs[rowB*SB + kB + 8] = pbA1;
      __syncthreads();
      if (k0 + 128 < g.K) {
        #pragma unroll
        for (int p=0;p<NCH;p++) paA[p] = *(const bf16x8*)(Abase + k0 + 128 + p*8);
        pbA0 = *(const bf16x8*)(Bbase + k0 + 128);
        pbA1 = *(const bf16x8*)(Bbase + k0 + 128 + 8);
      }
      compute(As, Bs);
    }
    if (k0 + 64 < g.K) {  // odd step: buffer 1, set B
      bf16* As = sh + BUF; bf16* Bs = sh + BUF + TM*SB;
      #pragma unroll
      for (int p=0;p<NCH;p++) *(bf16x8*)&As[rowA*SB + kA + p*8] = paB[p];
      *(bf16x8*)&Bs[rowB*SB + kB]     = pbB0;
      *(bf16x8*)&Bs[rowB*SB + kB + 8] = pbB1;
      __syncthreads();
      if (k0 + 192 < g.K) {
        #pragma unroll
        for (int p=0;p<NCH;p++) paB[p] = *(const bf16x8*)(Abase + k0 + 192 + p*8);
        pbB0 = *(const bf16x8*)(Bbase + k0 + 192);
        pbB1 = *(const bf16x8*)(Bbase + k0 + 192 + 8);
      }
      compute(As, Bs);
    }
  }

  float clv = 0.f;
  if (mode == 10) clv = *(g.clp + (long)bz*g.sClp);

  // mode 12 tile address precompute (block-uniform)
  bf16* Pt12 = (bf16*)0; int slotl0 = 0;
  if (mode == 12) {
    const int d = (row0 & ~127) - col0;      // in {-64,0,64,...}
    const int slot = (d + 64) >> 7;
    slotl0 = (row0 & ~127) - slot*128;
    Pt12 = Cb + ((long)bm*3 + slot) * (64*128);
  }

  // hasT is block-uniform (mode, col0) -> safe around __syncthreads
  const bool hasT = (mode==1 || mode==2 || mode==3) ||
                    (mode==11 && col0 >= 256 && col0 < 512);

  #pragma unroll
  for (int i=0;i<NI;i++){
    const int rb = row0 + wr + i*16 + quad*4;
    const int rloc = wr + i*16 + quad*4;
    #pragma unroll
    for (int j=0;j<2;j++){
      const int c = col0 + wc + j*16 + l15;
      const int cloc = wc + j*16 + l15;
      bf16 tv[4], tv2[4]; bool doT = false, doT2 = false;
      #pragma unroll
      for (int reg=0; reg<4; reg++){
        const int r = rb + reg;
        float v = acc[i][j][reg];
        const long co = (long)r*g.ldc + c;
        switch (mode) {
          case 1: {
            Cb[co]  = (bf16)v;
            float sv = silu_f(v);
            Cb2[co] = (bf16)sv;
            tv[reg] = (bf16)(sv * rowv[r]); doT = true;
          } break;
          case 2: {
            bf16 o = (bf16)(v - auxf[(long)r*g.ldax + c]);
            Cb[co] = o; tv[reg] = o; doT = true;
          } break;
          case 3: {
            float v3 = silu_bwd_f((float)auxb[(long)r*g.ldax + c]) * v * rowv[r];
            tv[reg]  = (bf16)v3;
            tv2[reg] = (bf16)(v3 * rowv2[r]);
            doT = true; doT2 = true;
          } break;
          case 10: {
            Cf[co] = v + auxf[(long)r*g.ldax + c]*clv;
          } break;
          case 11: {
            float o = v + g.bqkv[c];
            if (c < 256)      g.Q [(long)r*256 + c]       = (bf16)o;
            else if (c < 512) { g.Ko[(long)r*256 + (c-256)] = (bf16)o; tv[reg] = (bf16)o; doT = true; }
            else              g.Vo[(long)r*256 + (c-512)] = o;
          } break;
          case 12: {
            const float cm = (float)cd[r];
            const float cl = (float)cd[c];
            float pv = -v * __expf(cm - cl);
            if (rowv) pv *= rowv[c];
            if (c > r) pv = 0.f;
            Pt12[(r - row0)*128 + (c - slotl0)] = (bf16)pv;
          } break;
        }
      }
      if (hasT && doT) {
        bf16x4 t4 = { tv[0], tv[1], tv[2], tv[3] };
        *(bf16x4*)&sh[cloc*TTP + rloc] = t4;
        if (doT2) {
          bf16x4 t4b = { tv2[0], tv2[1], tv2[2], tv2[3] };
          *(bf16x4*)&sh[64*72 + cloc*TTP + rloc] = t4b;
        }
      }
    }
  }

  // coalesced transposed write-back through LDS
  if (hasT) {
    __syncthreads();
    const int cl = tid >> 2, rl = (tid & 3)*16;
    bf16x8 u0 = *(const bf16x8*)&sh[cl*72 + rl];
    bf16x8 u1 = *(const bf16x8*)&sh[cl*72 + rl + 8];
    bf16* d;
    if (mode == 11) {
      // Kt[b][c-256][l]; row0 never crosses a batch boundary (64 | 2048)
      const int b = row0 >> 11, l0r = row0 & 2047;
      d = Ct + (long)b*g.sCt + (long)(col0-256+cl)*g.ldct + l0r + rl;
    } else {
      d = Ct + (long)(col0+cl)*g.ldct + row0 + rl;
    }
    *(bf16x8*)d       = u0;
    *(bf16x8*)(d + 8) = u1;
    if (mode == 3) {
      bf16x8 v0 = *(const bf16x8*)&sh[64*72 + cl*72 + rl];
      bf16x8 v1 = *(const bf16x8*)&sh[64*72 + cl*72 + rl + 8];
      bf16* d2 = Ct2 + (long)(col0+cl)*g.ldct + row0 + rl;
      *(bf16x8*)d2       = v0;
      *(bf16x8*)(d2 + 8) = v1;
    }
  }
  __syncthreads();   // persistent block: protect sh before next job
}

// pgen half-tile dispatch: returns true (with bn set) if the half-tile must be computed;
// zero-fills the read-but-fully-masked half; returns false if consumer won't read the slot.
__device__ __forceinline__ bool pgen_prep(const MArgs& g, int mt, int hs, int bz, int& bnOut)
{
  const int slot = hs >> 1, half = hs & 1;
  const int m0 = mt*64;
  const int l0 = (m0 & ~127) - slot*128;
  if (l0 < 0) return false;
  const double* cd = g.cd + (long)bz*g.sCd;
  const int lref = (l0+127 < m0) ? (l0+127) : m0;
  if (cd[m0] - cd[lref] < CUTOFF) return false;
  const int l0h = l0 + half*64;
  if (l0h > m0) {
    bf16* Pt = g.Cb + (long)bz*g.sCb + ((long)mt*3 + slot) * (64*128);
    const int row = threadIdx.x >> 2, colb = 64 + (threadIdx.x & 3)*16;
    bf16x8 z;
    #pragma unroll
    for (int q=0;q<8;q++) z[q] = (bf16)0.f;
    *(bf16x8*)&Pt[row*128 + colb]     = z;
    *(bf16x8*)&Pt[row*128 + colb + 8] = z;
    return false;
  }
  bnOut = l0h >> 6;
  return true;
}

// ===================== consumer job: O = wdc[m]*(A.W^T) + sum_slots P.B2 =====================
struct CArgs {
  const bf16 *A, *W, *P, *B2;
  long sA, sW, sB2;
  int ldb2;
  const double* cd; long sCd;
  const float* wdc; long sWdc;
  float* Cf; long sCf;
  bf16* Cb; long sCb;
  int ldc;
};

template<int KS64, int SILU, int ZSPLIT>
__device__ __forceinline__ void cons_body(const CArgs& g, int mt, int ny, int zz, bf16* sh)
{
  const int m0 = mt*64, n0 = ny*64;
  const int bz   = ZSPLIT ? (zz >> 1) : zz;
  const int half = ZSPLIT ? (zz & 1)  : 0;
  const int K1 = KS64*64;
  const bf16* A  = g.A  + (long)bz*g.sA;
  const bf16* W  = g.W  + (long)bz*g.sW;
  const bf16* B2 = g.B2 + (long)bz*g.sB2;
  const double* cd = g.cd + (long)bz*g.sCd;
  const float* wdc = g.wdc + (long)bz*g.sWdc;

  const int tid = threadIdx.x;
  const int lane = tid & 63, w = tid >> 6;
  const int wr = (w>>1)*32, wc = (w&1)*32;
  const int l15 = lane & 15, quad = lane >> 4;
  const int rowA = tid >> 2, kA = (tid & 3) * 16;

  bool alive[3];
  int nalive = 0;
  #pragma unroll
  for (int s=0;s<3;s++){
    const int l0 = (m0 & ~127) - s*128;
    bool a = (l0 >= 0);
    if (a) {
      const int lref = (l0+127 < m0) ? (l0+127) : m0;
      a = (cd[m0] - cd[lref] >= CUTOFF);
    }
    alive[s] = a; nalive += a ? 1 : 0;
  }
  if (ZSPLIT && half == 1 && nalive == 0) return;   // no sh touched yet: safe skip

  constexpr int BUFC = 128*SB;

  f32x4 O[2][2];
  #pragma unroll
  for (int i=0;i<2;i++)
    #pragma unroll
    for (int j=0;j<2;j++)
      #pragma unroll
      for (int r=0;r<4;r++) O[i][j][r] = 0.f;

  auto compute = [&](const bf16* As, const bf16* Bs){
    #pragma unroll
    for (int ch=0; ch<2; ch++){
      bf16x8 af[2], bfr[2];
      #pragma unroll
      for (int i=0;i<2;i++) af[i]  = *(const bf16x8*)&As[(wr + i*16 + l15)*SB + ch*32 + quad*8];
      #pragma unroll
      for (int j=0;j<2;j++) bfr[j] = *(const bf16x8*)&Bs[(wc + j*16 + l15)*SB + ch*32 + quad*8];
      #pragma unroll
      for (int i=0;i<2;i++)
        #pragma unroll
        for (int j=0;j<2;j++)
          O[i][j] = __builtin_amdgcn_mfma_f32_16x16x32_bf16(af[i], bfr[j], O[i][j], 0, 0, 0);
    }
  };

  if (half == 0) {
    const bf16* Abase = A + (long)(m0+rowA)*K1 + kA;
    const bf16* Wbase = W + (long)(n0+rowA)*K1 + kA;
    bf16x8 aA0,aA1,wA0,wA1, aB0,aB1,wB0,wB1;
    aA0 = *(const bf16x8*)Abase;        aA1 = *(const bf16x8*)(Abase + 8);
    wA0 = *(const bf16x8*)Wbase;        wA1 = *(const bf16x8*)(Wbase + 8);
    aB0 = *(const bf16x8*)(Abase + 64); aB1 = *(const bf16x8*)(Abase + 72);
    wB0 = *(const bf16x8*)(Wbase + 64); wB1 = *(const bf16x8*)(Wbase + 72);
    for (int ks=0; ks<KS64; ks+=2){
      {
        bf16* As = sh; bf16* Bs = sh + 64*SB;
        *(bf16x8*)&As[rowA*SB + kA]     = aA0;
        *(bf16x8*)&As[rowA*SB + kA + 8] = aA1;
        *(bf16x8*)&Bs[rowA*SB + kA]     = wA0;
        *(bf16x8*)&Bs[rowA*SB + kA + 8] = wA1;
        __syncthreads();
        if (ks+2 < KS64) {
          const int kn = (ks+2)*64;
          aA0 = *(const bf16x8*)(Abase + kn); aA1 = *(const bf16x8*)(Abase + kn + 8);
          wA0 = *(const bf16x8*)(Wbase + kn); wA1 = *(const bf16x8*)(Wbase + kn + 8);
        }
        compute(As, Bs);
      }
      {
        bf16* As = sh + BUFC; bf16* Bs = sh + BUFC + 64*SB;
        *(bf16x8*)&As[rowA*SB + kA]     = aB0;
        *(bf16x8*)&As[rowA*SB + kA + 8] = aB1;
        *(bf16x8*)&Bs[rowA*SB + kA]     = wB0;
        *(bf16x8*)&Bs[rowA*SB + kA + 8] = wB1;
        __syncthreads();
        if (ks+3 < KS64) {
          const int kn = (ks+3)*64;
          aB0 = *(const bf16x8*)(Abase + kn); aB1 = *(const bf16x8*)(Abase + kn + 8);
          wB0 = *(const bf16x8*)(Wbase + kn); wB1 = *(const bf16x8*)(Wbase + kn + 8);
        }
        compute(As, Bs);
      }
    }
    #pragma unroll
    for (int i=0;i<2;i++)
      #pragma unroll
      for (int reg=0; reg<4; reg++){
        const float s = wdc[m0 + wr + i*16 + quad*4 + reg];
        #pragma unroll
        for (int j=0;j<2;j++) O[i][j][reg] *= s;
      }
  }

  if (!ZSPLIT || half == 1) {
    int s0a=0, s1a=0, s2a=0, na=0;
    #pragma unroll
    for (int s=0;s<3;s++) if (alive[s]) { if (na==0) s0a=s; else if (na==1) s1a=s; else s2a=s; na++; }
    const int nst = na*2;
    if (nst > 0) {
      auto Pptr = [&](int t)->const bf16* {
        const int i = t>>1;
        const int s = (i==0) ? s0a : ((i==1) ? s1a : s2a);
        return g.P + (((long)bz*32 + mt)*3 + s)*(64*128) + (long)rowA*128 + (t&1)*64 + kA;
      };
      auto Bptr = [&](int t)->const bf16* {
        const int i = t>>1;
        const int s = (i==0) ? s0a : ((i==1) ? s1a : s2a);
        const int l0 = (m0 & ~127) - s*128;
        return B2 + (long)(n0+rowA)*g.ldb2 + l0 + (t&1)*64 + kA;
      };
      bf16x8 pA0,pA1,bA0,bA1, pB0,pB1,bB0,bB1;
      { const bf16* pp = Pptr(0); pA0 = *(const bf16x8*)pp; pA1 = *(const bf16x8*)(pp+8);
        const bf16* bb = Bptr(0); bA0 = *(const bf16x8*)bb; bA1 = *(const bf16x8*)(bb+8); }
      { const bf16* pp = Pptr(1); pB0 = *(const bf16x8*)pp; pB1 = *(const bf16x8*)(pp+8);
        const bf16* bb = Bptr(1); bB0 = *(const bf16x8*)bb; bB1 = *(const bf16x8*)(bb+8); }
      for (int t=0; t<nst; t+=2){
        {
          bf16* As = sh; bf16* Bs = sh + 64*SB;
          *(bf16x8*)&As[rowA*SB + kA]     = pA0;
          *(bf16x8*)&As[rowA*SB + kA + 8] = pA1;
          *(bf16x8*)&Bs[rowA*SB + kA]     = bA0;
          *(bf16x8*)&Bs[rowA*SB + kA + 8] = bA1;
          __syncthreads();
          if (t+2 < nst) {
            const bf16* pp = Pptr(t+2); pA0 = *(const bf16x8*)pp; pA1 = *(const bf16x8*)(pp+8);
            const bf16* bb = Bptr(t+2); bA0 = *(const bf16x8*)bb; bA1 = *(const bf16x8*)(bb+8);
          }
          compute(As, Bs);
        }
        {
          bf16* As = sh + BUFC; bf16* Bs = sh + BUFC + 64*SB;
          *(bf16x8*)&As[rowA*SB + kA]     = pB0;
          *(bf16x8*)&As[rowA*SB + kA + 8] = pB1;
          *(bf16x8*)&Bs[rowA*SB + kA]     = bB0;
          *(bf16x8*)&Bs[rowA*SB + kA + 8] = bB1;
          __syncthreads();
          if (t+3 < nst) {
            const bf16* pp = Pptr(t+3); pB0 = *(const bf16x8*)pp; pB1 = *(const bf16x8*)(pp+8);
            const bf16* bb = Bptr(t+3); bB0 = *(const bf16x8*)bb; bB1 = *(const bf16x8*)(bb+8);
          }
          compute(As, Bs);
        }
      }
    }
  }

  #pragma unroll
  for (int i=0;i<2;i++){
    const int rb = m0 + wr + i*16 + quad*4;
    #pragma unroll
    for (int j=0;j<2;j++){
      const int c = n0 + wc + j*16 + l15;
      #pragma unroll
      for (int reg=0; reg<4; reg++){
        const long co = (long)(rb+reg)*g.ldc + c;
        if (ZSPLIT)     unsafeAtomicAdd(&g.Cf[(long)bz*g.sCf + co], O[i][j][reg]);
        else if (SILU)  g.Cb[(long)bz*g.sCb + co] = (bf16)silu_f(O[i][j][reg]);
        else            g.Cf[(long)bz*g.sCf + co] = O[i][j][reg];
      }
    }
  }
  __syncthreads();   // persistent block: protect sh before next job
}

// ===================== cumsum job (per-batch fp64 scan + derived) =====================
struct CumArgs {
  const float* lw; const float* lr;
  double* cd; float* wdc; float* se1; float* se2; int L;
};

__device__ __forceinline__ void cumsum_body(const CumArgs& a, int b, bf16* shraw)
{
  double* sum_s = (double*)shraw;    // 2048 B of the shared scratch
  const int t = threadIdx.x;
  const int L = a.L;
  const float* lwb = a.lw + (long)b*L;
  double loc[8];
  double s = 0.0;
  #pragma unroll
  for (int i=0;i<8;i++){ s += (double)lwb[t*8+i]; loc[i] = s; }
  sum_s[t] = s;
  __syncthreads();
  for (int off=1; off<256; off<<=1){
    double v = 0.0;
    if (t >= off) v = sum_s[t-off];
    __syncthreads();
    sum_s[t] += v;
    __syncthreads();
  }
  const double prefix = (t > 0) ? sum_s[t-1] : 0.0;
  const double total  = sum_s[255];
  #pragma unroll
  for (int i=0;i<8;i++){
    double c = prefix + loc[i];
    long idx = (long)b*L + t*8 + i;
    a.cd[idx]  = c;
    a.wdc[idx] = (float)exp(c);
    double e = exp(total - c);
    a.se1[idx] = (float)(-e);
    a.se2[idx] = (float)(-e) * a.lr[idx];
  }
  __syncthreads();   // protect sh before next job
}

// ===================== front jobs: 1D ladder =====================
// [0,1024) conv x | [1024,1280) conv W1 | [1280,1536) conv W2 | [1536,2560) zero out0
// [2560,2608) transpose Wqkv | [2608,2736) transpose W2 | [2736,4784) scalar_proj | [4784] bqkv
struct FrontArgs {
  const float *x, *W1, *W2, *Wq, *Wk, *Wv;
  bf16 *xb, *W1b, *W2b, *Wqkvt, *W2t;
  float* out0;
  const float *wlr, *blr, *wwd, *bwd, *lbl, *lbw;
  float *lr, *lw;
  const float *bq, *bk, *bv; float* bqkv;
  long LD4, HD4, HD;
};

__device__ __forceinline__ void front_body(const FrontArgs& f, int bid, bf16* shraw)
{
  bf16 (*t)[72] = reinterpret_cast<bf16(*)[72]>(shraw);
  const int tid = threadIdx.x;

  if (bid < 1536) {
    const float* src; bf16* dst; long n; long base;
    if (bid < 1024)      { src = f.x;  dst = f.xb;  n = f.LD4; base = (long)bid*2048; }
    else if (bid < 1280) { src = f.W1; dst = f.W1b; n = f.HD4; base = (long)(bid-1024)*2048; }
    else                 { src = f.W2; dst = f.W2b; n = f.HD4; base = (long)(bid-1280)*2048; }
    long i = base + (long)tid*8;
    if (i >= n) return;
    float4 a = *(const float4*)&src[i];
    float4 b = *(const float4*)&src[i+4];
    bf16x8 o;
    o[0]=(bf16)a.x; o[1]=(bf16)a.y; o[2]=(bf16)a.z; o[3]=(bf16)a.w;
    o[4]=(bf16)b.x; o[5]=(bf16)b.y; o[6]=(bf16)b.z; o[7]=(bf16)b.w;
    *(bf16x8*)&dst[i] = o;
    return;
  }
  if (bid < 2560) {
    long i = (long)(bid-1536)*2048 + (long)tid*8;
    float4 z = {0.f,0.f,0.f,0.f};
    *(float4*)&f.out0[i]   = z;
    *(float4*)&f.out0[i+4] = z;
    return;
  }
  if (bid < 2736) {
    const float* ip; bf16* op; int R, C; int r0, c0;
    if (bid < 2608) {
      const int r = bid - 2560;
      const int z = r >> 4, rem = r & 15;
      ip = z==0 ? f.Wq : (z==1 ? f.Wk : f.Wv);
      op = f.Wqkvt + (long)z*256*256;
      R = 256; C = 256;
      r0 = (rem & 3)*64; c0 = (rem >> 2)*64;
    } else {
      const int r = bid - 2608;
      const int b = r >> 5, rem = r & 31;
      ip = f.W2 + (long)b*f.HD;
      op = f.W2t + (long)b*f.HD;
      R = 256; C = 512;
      r0 = (rem & 3)*64; c0 = (rem >> 2)*64;
    }
    const int lr_ = tid>>2, lc = (tid&3)*16;
    #pragma unroll
    for (int q=0;q<4;q++){
      float4 a = *(const float4*)&ip[(long)(r0+lr_)*C + c0+lc + q*4];
      t[lr_][lc+q*4+0] = (bf16)a.x; t[lr_][lc+q*4+1] = (bf16)a.y;
      t[lr_][lc+q*4+2] = (bf16)a.z; t[lr_][lc+q*4+3] = (bf16)a.w;
    }
    __syncthreads();
    const int oc = tid>>2, orr = (tid&3)*16;
    bf16x8 u, v;
    #pragma unroll
    for (int i=0;i<8;i++){ u[i] = t[orr+i][oc]; v[i] = t[orr+8+i][oc]; }
    *(bf16x8*)&op[(long)(c0+oc)*R + r0+orr]   = u;
    *(bf16x8*)&op[(long)(c0+oc)*R + r0+orr+8] = v;
    __syncthreads();   // protect sh before next job
    return;
  }
  if (bid < 4784) {
    const int row  = (bid-2736)*4 + (tid >> 6);
    const int lane = tid & 63;
    const float4 a = ((const float4*)(f.x + (long)row*256))[lane];
    const float4 u = ((const float4*)f.wlr)[lane];
    const float4 w = ((const float4*)f.wwd)[lane];
    float d1 = a.x*u.x + a.y*u.y + a.z*u.z + a.w*u.w;
    float d2 = a.x*w.x + a.y*w.y + a.z*w.z + a.w*w.w;
    #pragma unroll
    for (int off=32; off; off>>=1) {
      d1 += __shfl_down(d1, off);
      d2 += __shfl_down(d2, off);
    }
    if (lane == 0) {
      float s1 = 1.f/(1.f+expf(-(d1 + f.blr[0])));
      f.lr[row] = expf(f.lbl[0]) * s1;
      float s2 = 1.f/(1.f+expf(-(d2 + f.bwd[0])));
      f.lw[row] = logf(1.f - expf(f.lbw[0]) * s2);
    }
    return;
  }
  for (int i = tid; i < 768; i += 256)
    f.bqkv[i] = (i<256) ? f.bq[i] : ((i<512) ? f.bk[i-256] : f.bv[i-512]);
}

// ===================== the persistent cooperative mega-kernel =====================
struct MegaArgs {
  FrontArgs f; CumArgs cu;
  MArgs qkv, z1, gz2, a1, p1, p2, w1n, w2n;
  CArgs c1, c2;
};

__global__ __launch_bounds__(256, 4)
void mega(MegaArgs ma)
{
  __shared__ __align__(16) bf16 sh[2*128*SB];   // 36864 B -> 4 blocks/CU
  cg::grid_group grid = cg::this_grid();
  const int nb = gridDim.x;

  // phase A: front matter
  for (int j = blockIdx.x; j < 4785; j += nb) front_body(ma.f, j, sh);
  __threadfence(); grid.sync();

  // phase C: cumsum (4) || QKV tiles (128 x 12, TM=64)
  for (int j = blockIdx.x; j < 1540; j += nb) {
    if (j < 4) cumsum_body(ma.cu, j, sh);
    else { const int q = j - 4; gemm_body<64>(ma.qkv, q & 127, q >> 7, 0, sh); }
  }
  __threadfence(); grid.sync();

  // phase D: Z1 (32 x 8 x 4)
  for (int j = blockIdx.x; j < 1024; j += nb)
    gemm_body<64>(ma.z1, j & 31, (j >> 5) & 7, j >> 8, sh);
  __threadfence(); grid.sync();

  // phase E: gZ2 (512) || P1 half-tiles (768)
  for (int j = blockIdx.x; j < 1280; j += nb) {
    if (j < 512) gemm_body<64>(ma.gz2, j & 31, (j >> 5) & 3, j >> 7, sh);
    else {
      const int i = j - 512;
      const int mt = i & 31, q = i >> 5;
      const int hs = q % 6, bz = q / 6;
      int bn;
      if (pgen_prep(ma.p1, mt, hs, bz, bn))
        gemm_body<64>(ma.p1, mt, bn, bz, sh);
    }
  }
  __threadfence(); grid.sync();

  // phase F: A1 (32 x 8 x 4)
  for (int j = blockIdx.x; j < 1024; j += nb)
    gemm_body<64>(ma.a1, j & 31, (j >> 5) & 7, j >> 8, sh);
  __threadfence(); grid.sync();

  // phase G: cons1 (32 x 8 x 4)
  for (int j = blockIdx.x; j < 1024; j += nb)
    cons_body<4,1,0>(ma.c1, j & 31, (j >> 5) & 7, j >> 8, sh);
  __threadfence(); grid.sync();

  // phase H: P2 half-tiles (768) || W1_next (128) || W2_next (128)
  for (int j = blockIdx.x; j < 1024; j += nb) {
    if (j < 768) {
      const int mt = j & 31, q = j >> 5;
      const int hs = q % 6, bz = q / 6;
      int bn;
      if (pgen_prep(ma.p2, mt, hs, bz, bn))
        gemm_body<64>(ma.p2, mt, bn, bz, sh);
    } else {
      const int i = j - 768;
      if (i < 128) gemm_body<64>(ma.w1n, i & 7, (i >> 3) & 3, i >> 5, sh);
      else { const int v = i - 128; gemm_body<64>(ma.w2n, v & 3, (v >> 2) & 7, v >> 5, sh); }
    }
  }
  __threadfence(); grid.sync();

  // phase I: cons2 z-split (32 x 4 x 8)
  for (int j = blockIdx.x; j < 1024; j += nb)
    cons_body<8,0,1>(ma.c2, j & 31, (j >> 5) & 3, j >> 7, sh);
}

extern "C" void kernel_launch(void* const* d_in, const int* in_sizes, int n_in,
                              void* d_out, int out_size, void* d_ws, size_t ws_size,
                              hipStream_t stream)
{
  const int Bn = 4, L = 2048, D = 256, H = 512;
  const long LD = (long)L*D, LH = (long)L*H, HD = (long)H*D;

  const float* x   = (const float*)d_in[0];
  const float* W1  = (const float*)d_in[1];
  const float* W2  = (const float*)d_in[2];
  const float* Wq  = (const float*)d_in[3];
  const float* bq  = (const float*)d_in[4];
  const float* Wk  = (const float*)d_in[5];
  const float* bk  = (const float*)d_in[6];
  const float* Wv  = (const float*)d_in[7];
  const float* bv  = (const float*)d_in[8];
  const float* wlr = (const float*)d_in[9];
  const float* blr = (const float*)d_in[10];
  const float* wwd = (const float*)d_in[11];
  const float* bwd = (const float*)d_in[12];
  const float* lbl = (const float*)d_in[13];
  const float* lbw = (const float*)d_in[14];
  (void)in_sizes; (void)n_in; (void)out_size; (void)ws_size;

  float* out0 = (float*)d_out;            // Z2_      [B,L,D]
  float* out1 = out0 + (long)Bn*LD;       // W1_next  [B,H,D]
  float* out2 = out1 + (long)Bn*HD;       // W2_next  [B,D,H]

  char* wsp = (char*)d_ws;
  size_t off = 0;
  auto alloc = [&](size_t bytes)->void*{
    void* p = wsp + off; off += (bytes + 255) & ~(size_t)255; return p;
  };
  bf16* xb    = (bf16*)alloc((size_t)Bn*LD*2);
  bf16* Wqkvt = (bf16*)alloc((size_t)3*D*D*2);
  float* bqkv = (float*)alloc((size_t)3*D*4);
  bf16* W1b  = (bf16*)alloc((size_t)Bn*HD*2);
  bf16* W2b  = (bf16*)alloc((size_t)Bn*HD*2);
  bf16* W2t  = (bf16*)alloc((size_t)Bn*HD*2);
  bf16* Qb   = (bf16*)alloc((size_t)Bn*LD*2);
  bf16* Kb   = (bf16*)alloc((size_t)Bn*LD*2);
  bf16* Kt   = (bf16*)alloc((size_t)Bn*LD*2);
  float* Vf  = (float*)alloc((size_t)Bn*LD*4);
  bf16* Z1b  = (bf16*)alloc((size_t)Bn*LH*2);
  bf16* X2b  = (bf16*)alloc((size_t)Bn*LH*2);
  bf16* X2t  = (bf16*)alloc((size_t)Bn*LH*2);   // pre-scaled by se2 (only used by W2_next)
  bf16* gZb  = (bf16*)alloc((size_t)Bn*LD*2);
  bf16* gZt  = (bf16*)alloc((size_t)Bn*LD*2);
  bf16* A1t  = (bf16*)alloc((size_t)Bn*LH*2);
  bf16* A1s  = (bf16*)alloc((size_t)Bn*LH*2);   // A1t pre-scaled by se1 (only used by W1_next)
  bf16* X2_b = (bf16*)alloc((size_t)Bn*LH*2);
  bf16* Pb1  = (bf16*)alloc((size_t)Bn*32*3*64*128*2);
  bf16* Pb2  = (bf16*)alloc((size_t)Bn*32*3*64*128*2);
  float* lrb = (float*)alloc((size_t)Bn*L*4);
  float* lwb = (float*)alloc((size_t)Bn*L*4);
  float* wdc = (float*)alloc((size_t)Bn*L*4);
  float* se1 = (float*)alloc((size_t)Bn*L*4);
  float* se2 = (float*)alloc((size_t)Bn*L*4);
  double* cdb = (double*)alloc((size_t)Bn*L*8);

  const long sP = (long)32*3*64*128;   // per-batch P stride (elems)

  MegaArgs ma{};

  // front
  ma.f.x = x; ma.f.W1 = W1; ma.f.W2 = W2; ma.f.Wq = Wq; ma.f.Wk = Wk; ma.f.Wv = Wv;
  ma.f.xb = xb; ma.f.W1b = W1b; ma.f.W2b = W2b; ma.f.Wqkvt = Wqkvt; ma.f.W2t = W2t;
  ma.f.out0 = out0;
  ma.f.wlr = wlr; ma.f.blr = blr; ma.f.wwd = wwd; ma.f.bwd = bwd; ma.f.lbl = lbl; ma.f.lbw = lbw;
  ma.f.lr = lrb; ma.f.lw = lwb;
  ma.f.bq = bq; ma.f.bk = bk; ma.f.bv = bv; ma.f.bqkv = bqkv;
  ma.f.LD4 = Bn*LD; ma.f.HD4 = Bn*HD; ma.f.HD = HD;

  // cumsum
  ma.cu = CumArgs{ lwb, lrb, cdb, wdc, se1, se2, L };

  // QKV (M spans all batches; TM=64)
  ma.qkv.A = xb; ma.qkv.lda = D; ma.qkv.B = Wqkvt; ma.qkv.ldb = D;
  ma.qkv.M = Bn*L; ma.qkv.N = 3*D; ma.qkv.K = D; ma.qkv.mode = 11; ma.qkv.ldc = 0;
  ma.qkv.Q = Qb; ma.qkv.Ko = Kb; ma.qkv.Vo = Vf; ma.qkv.bqkv = bqkv;
  ma.qkv.Ct = Kt; ma.qkv.sCt = LD; ma.qkv.ldct = L;

  // Z1
  ma.z1.A = Kb; ma.z1.lda = D; ma.z1.sA = LD; ma.z1.B = W1b; ma.z1.ldb = D; ma.z1.sB = HD;
  ma.z1.M = L; ma.z1.N = H; ma.z1.K = D; ma.z1.mode = 1; ma.z1.ldc = H;
  ma.z1.Cb = Z1b; ma.z1.sCb = LH; ma.z1.Cb2 = X2b; ma.z1.sCb2 = LH;
  ma.z1.Ct = X2t; ma.z1.sCt = LH; ma.z1.ldct = L;
  ma.z1.rowv = se2; ma.z1.sRowv = L;

  // gZ2
  ma.gz2.A = X2b; ma.gz2.lda = H; ma.gz2.sA = LH; ma.gz2.B = W2b; ma.gz2.ldb = H; ma.gz2.sB = HD;
  ma.gz2.M = L; ma.gz2.N = D; ma.gz2.K = H; ma.gz2.mode = 2; ma.gz2.ldc = D;
  ma.gz2.auxf = Vf; ma.gz2.ldax = D; ma.gz2.sAuxf = LD; ma.gz2.Cb = gZb; ma.gz2.sCb = LD;
  ma.gz2.Ct = gZt; ma.gz2.sCt = LD; ma.gz2.ldct = L;

  // A1
  ma.a1.A = gZb; ma.a1.lda = D; ma.a1.sA = LD; ma.a1.B = W2t; ma.a1.ldb = D; ma.a1.sB = HD;
  ma.a1.M = L; ma.a1.N = H; ma.a1.K = D; ma.a1.mode = 3; ma.a1.ldc = H;
  ma.a1.auxb = Z1b; ma.a1.ldax = H; ma.a1.sAuxb = LH;
  ma.a1.rowv = lrb; ma.a1.sRowv = L; ma.a1.rowv2 = se1; ma.a1.sRowv2 = L;
  ma.a1.Ct = A1t; ma.a1.sCt = LH; ma.a1.ldct = L;
  ma.a1.Ct2 = A1s; ma.a1.sCt2 = LH;

  // P1 (mode 12 half-tiles)
  ma.p1.A = Qb; ma.p1.lda = D; ma.p1.sA = LD; ma.p1.B = Kb; ma.p1.ldb = D; ma.p1.sB = LD;
  ma.p1.K = D; ma.p1.mode = 12; ma.p1.ldc = 0;
  ma.p1.Cb = Pb1; ma.p1.sCb = sP;
  ma.p1.cd = cdb; ma.p1.sCd = L;

  // P2 (mode 12 half-tiles, lr-scaled)
  ma.p2.A = X2_b; ma.p2.lda = H; ma.p2.sA = LH; ma.p2.B = X2b; ma.p2.ldb = H; ma.p2.sB = LH;
  ma.p2.K = H; ma.p2.mode = 12; ma.p2.ldc = 0;
  ma.p2.Cb = Pb2; ma.p2.sCb = sP;
  ma.p2.cd = cdb; ma.p2.sCd = L;
  ma.p2.rowv = lrb; ma.p2.sRowv = L;

  // W1_next
  ma.w1n.A = A1s; ma.w1n.lda = L; ma.w1n.sA = LH; ma.w1n.B = Kt; ma.w1n.ldb = L; ma.w1n.sB = LD;
  ma.w1n.M = H; ma.w1n.N = D; ma.w1n.K = L; ma.w1n.mode = 10; ma.w1n.ldc = D;
  ma.w1n.cd = cdb; ma.w1n.sCd = L;
  ma.w1n.auxf = W1; ma.w1n.ldax = D; ma.w1n.sAuxf = HD; ma.w1n.clp = wdc + (L-1); ma.w1n.sClp = L;
  ma.w1n.Cf = out1; ma.w1n.sCf = HD;

  // W2_next
  ma.w2n.A = gZt; ma.w2n.lda = L; ma.w2n.sA = LD; ma.w2n.B = X2t; ma.w2n.ldb = L; ma.w2n.sB = LH;
  ma.w2n.M = D; ma.w2n.N = H; ma.w2n.K = L; ma.w2n.mode = 10; ma.w2n.ldc = H;
  ma.w2n.cd = cdb; ma.w2n.sCd = L;
  ma.w2n.auxf = W2; ma.w2n.ldax = H; ma.w2n.sAuxf = HD; ma.w2n.clp = wdc + (L-1); ma.w2n.sClp = L;
  ma.w2n.Cf = out2; ma.w2n.sCf = HD;

  // cons1
  ma.c1.A = Qb; ma.c1.sA = LD; ma.c1.W = W1b; ma.c1.sW = HD;
  ma.c1.P = Pb1; ma.c1.B2 = A1t; ma.c1.sB2 = LH; ma.c1.ldb2 = L;
  ma.c1.cd = cdb; ma.c1.sCd = L; ma.c1.wdc = wdc; ma.c1.sWdc = L;
  ma.c1.Cb = X2_b; ma.c1.sCb = LH; ma.c1.ldc = H;

  // cons2
  ma.c2.A = X2_b; ma.c2.sA = LH; ma.c2.W = W2b; ma.c2.sW = HD;
  ma.c2.P = Pb2; ma.c2.B2 = gZt; ma.c2.sB2 = LD; ma.c2.ldb2 = L;
  ma.c2.cd = cdb; ma.c2.sCd = L; ma.c2.wdc = wdc; ma.c2.sWdc = L;
  ma.c2.Cf = out0; ma.c2.sCf = LD; ma.c2.ldc = D;

  int maxb = 0;
  hipOccupancyMaxActiveBlocksPerMultiprocessor(&maxb, mega, 256, 0);
  if (maxb < 1) maxb = 1;
  int nblk = maxb * 256;
  if (nblk > 1024) nblk = 1024;

  void* kargs[] = { (void*)&ma };
  hipLaunchCooperativeKernel((const void*)mega, dim3(nblk), dim3(256), kargs, 0, stream);
}

// Round 8
// 218.300 us; speedup vs baseline: 5.9754x; 5.9754x over previous
//
#include <hip/hip_runtime.h>

typedef __bf16 bf16;
typedef __bf16 bf16x8 __attribute__((ext_vector_type(8)));
typedef __bf16 bf16x4 __attribute__((ext_vector_type(4)));
typedef float  f32x4  __attribute__((ext_vector_type(4)));

#define SB 72    // LDS row stride (elems) for 64-wide k tiles
#define CUTOFF -18.0

__device__ __forceinline__ float silu_f(float x){
  float s = 1.f/(1.f+__expf(-x));
  return x*s;
}
__device__ __forceinline__ float silu_bwd_f(float x){
  float s = 1.f/(1.f+__expf(-x));
  float si = x*s;
  return si + s*(1.f-si);
}

// ===================== generic TMx64 MFMA GEMM (NT), BK=64, depth-2 prefetch + LDS dbuf =====================
struct MArgs {
  const bf16* A; const bf16* B;
  long sA, sB;
  int lda, ldb;
  int M, N, K;
  int mode;
  float* Cf; long sCf;
  bf16*  Cb; long sCb;
  bf16*  Cb2; long sCb2;
  bf16*  Ct;  long sCt;  int ldct;   // transposed output (coalesced via LDS)
  bf16*  Ct2; long sCt2;             // second (scaled) transposed output (mode 3)
  int ldc;
  const float* auxf; int ldax; long sAuxf;
  const bf16*  auxb; long sAuxb;
  const float* rowv; long sRowv;     // mode 1: se2 scale for Ct; mode 3: lr
  const float* rowv2; long sRowv2;   // mode 3: se1 scale for Ct2
  const double* cd;  long sCd;       // mode 10: dead-K-prefix skip
  const float* clp;  long sClp;
  bf16* Q; bf16* Ko; float* Vo; const float* bqkv;   // mode 11
};

// modes: 1  Cb=acc, Cb2=silu(acc), Ct=(silu(acc)*rowv[r])^T
//        2  Cb=acc-auxf[r,c], Ct same^T
//        3  v3=silu_bwd(auxb)*acc*rowv[r]; Ct=v3^T, Ct2=(v3*rowv2[r])^T
//        10 Cf=acc+auxf[r,c]*clv  (inputs pre-scaled; dead k-prefix skipped via cd)
//        11 QKV: c<256->Q, <512->Ko (+Ct=Kt), else->Vo (+bias)
// NOTE (dbuf): all transpose-epilogue users (modes 1/2/3 K in {256,512}, mode 11 K=256)
// run an EVEN number of K-steps, so the last MFMA reads buffer 1 while the transpose
// tile lives in buffer 0 — no race with the single-barrier loop.
template<int TM>
__device__ __forceinline__ void gemm_body(const MArgs& g, int bm, int bn, int bz)
{
  constexpr int BUF = (TM+64)*SB;
  __shared__ __align__(16) bf16 sh[2*BUF];

  const int row0 = bm*TM, col0 = bn*64;
  constexpr int NI  = TM/32;
  constexpr int TPR = 256/TM;
  constexpr int EPR = 64/TPR;
  constexpr int NCH = EPR/8;

  const bf16* A = g.A + (long)bz*g.sA;
  const bf16* B = g.B + (long)bz*g.sB;
  const double* cd = g.cd ? g.cd + (long)bz*g.sCd : (const double*)0;
  float* Cf = g.Cf ? g.Cf + (long)bz*g.sCf : (float*)0;
  bf16* Cb  = g.Cb ? g.Cb + (long)bz*g.sCb : (bf16*)0;
  bf16* Cb2 = g.Cb2 ? g.Cb2 + (long)bz*g.sCb2 : (bf16*)0;
  bf16* Ct  = g.Ct ? g.Ct + (long)bz*g.sCt : (bf16*)0;
  bf16* Ct2 = g.Ct2 ? g.Ct2 + (long)bz*g.sCt2 : (bf16*)0;
  const float* auxf = g.auxf ? g.auxf + (long)bz*g.sAuxf : (const float*)0;
  const bf16*  auxb = g.auxb ? g.auxb + (long)bz*g.sAuxb : (const bf16*)0;
  const float* rowv = g.rowv ? g.rowv + (long)bz*g.sRowv : (const float*)0;
  const float* rowv2 = g.rowv2 ? g.rowv2 + (long)bz*g.sRowv2 : (const float*)0;

  const int tid = threadIdx.x;
  const int mode = g.mode;
  const int lane = tid & 63;
  const int w = tid >> 6;
  const int wr = (w >> 1) * (TM/2), wc = (w & 1) * 32;
  const int l15 = lane & 15;
  const int quad = lane >> 4;

  f32x4 acc[NI][2];
  #pragma unroll
  for (int i=0;i<NI;i++)
    #pragma unroll
    for (int j=0;j<2;j++)
      #pragma unroll
      for (int r=0;r<4;r++) acc[i][j][r] = 0.f;

  const int rowA = tid / TPR, kA = (tid % TPR) * EPR;
  const int rowB = tid >> 2,  kB = (tid & 3) * 16;

  // ---- ballot-parallel dead-prefix scan (mode 10): lane l tests 64-chunk l
  int klo = 0;
  if (cd) {
    const double cref = cd[g.K-1];
    const int nch = g.K >> 6;
    bool dead = (lane < nch-1) && ((cref - cd[lane*64+63]) < CUTOFF);
    unsigned long long mask = __ballot(dead);
    klo = (int)__builtin_ctzll(~mask) * 64;
  }

  const bf16* Abase = A + (long)(row0+rowA)*g.lda + kA;
  const bf16* Bbase = B + (long)(col0+rowB)*g.ldb + kB;

  // depth-2 prefetch: two named register sets (no runtime indexing -> no scratch)
  bf16x8 paA[NCH], pbA0, pbA1, paB[NCH], pbB0, pbB1;
  #pragma unroll
  for (int p=0;p<NCH;p++) paA[p] = *(const bf16x8*)(Abase + klo + p*8);
  pbA0 = *(const bf16x8*)(Bbase + klo);
  pbA1 = *(const bf16x8*)(Bbase + klo + 8);
  if (klo + 64 < g.K) {
    #pragma unroll
    for (int p=0;p<NCH;p++) paB[p] = *(const bf16x8*)(Abase + klo + 64 + p*8);
    pbB0 = *(const bf16x8*)(Bbase + klo + 64);
    pbB1 = *(const bf16x8*)(Bbase + klo + 64 + 8);
  }

  auto compute = [&](const bf16* As, const bf16* Bs){
    #pragma unroll
    for (int ch=0; ch<2; ch++){
      bf16x8 af[NI], bf2[2];
      #pragma unroll
      for (int i=0;i<NI;i++) af[i]  = *(const bf16x8*)&As[(wr + i*16 + l15)*SB + ch*32 + quad*8];
      #pragma unroll
      for (int j=0;j<2;j++) bf2[j] = *(const bf16x8*)&Bs[(wc + j*16 + l15)*SB + ch*32 + quad*8];
      #pragma unroll
      for (int i=0;i<NI;i++)
        #pragma unroll
        for (int j=0;j<2;j++)
          acc[i][j] = __builtin_amdgcn_mfma_f32_16x16x32_bf16(af[i], bf2[j], acc[i][j], 0, 0, 0);
    }
  };

  for (int k0 = klo; k0 < g.K; k0 += 128) {
    {  // even step: buffer 0, set A
      bf16* As = sh; bf16* Bs = sh + TM*SB;
      #pragma unroll
      for (int p=0;p<NCH;p++) *(bf16x8*)&As[rowA*SB + kA + p*8] = paA[p];
      *(bf16x8*)&Bs[rowB*SB + kB]     = pbA0;
      *(bf16x8*)&Bs[rowB*SB + kB + 8] = pbA1;
      __syncthreads();
      if (k0 + 128 < g.K) {
        #pragma unroll
        for (int p=0;p<NCH;p++) paA[p] = *(const bf16x8*)(Abase + k0 + 128 + p*8);
        pbA0 = *(const bf16x8*)(Bbase + k0 + 128);
        pbA1 = *(const bf16x8*)(Bbase + k0 + 128 + 8);
      }
      compute(As, Bs);
    }
    if (k0 + 64 < g.K) {  // odd step: buffer 1, set B
      bf16* As = sh + BUF; bf16* Bs = sh + BUF + TM*SB;
      #pragma unroll
      for (int p=0;p<NCH;p++) *(bf16x8*)&As[rowA*SB + kA + p*8] = paB[p];
      *(bf16x8*)&Bs[rowB*SB + kB]     = pbB0;
      *(bf16x8*)&Bs[rowB*SB + kB + 8] = pbB1;
      __syncthreads();
      if (k0 + 192 < g.K) {
        #pragma unroll
        for (int p=0;p<NCH;p++) paB[p] = *(const bf16x8*)(Abase + k0 + 192 + p*8);
        pbB0 = *(const bf16x8*)(Bbase + k0 + 192);
        pbB1 = *(const bf16x8*)(Bbase + k0 + 192 + 8);
      }
      compute(As, Bs);
    }
  }

  float clv = 0.f;
  if (mode == 10) clv = *(g.clp + (long)bz*g.sClp);

  // hasT is block-uniform (mode, col0) -> safe around __syncthreads
  const bool hasT = (mode==1 || mode==2 || mode==3) ||
                    (mode==11 && col0 >= 256 && col0 < 512);

  #pragma unroll
  for (int i=0;i<NI;i++){
    const int rb = row0 + wr + i*16 + quad*4;
    const int rloc = wr + i*16 + quad*4;
    #pragma unroll
    for (int j=0;j<2;j++){
      const int c = col0 + wc + j*16 + l15;
      const int cloc = wc + j*16 + l15;
      bf16 tv[4], tv2[4]; bool doT = false, doT2 = false;
      #pragma unroll
      for (int reg=0; reg<4; reg++){
        const int r = rb + reg;
        float v = acc[i][j][reg];
        const long co = (long)r*g.ldc + c;
        switch (mode) {
          case 1: {
            Cb[co]  = (bf16)v;
            float sv = silu_f(v);
            Cb2[co] = (bf16)sv;
            tv[reg] = (bf16)(sv * rowv[r]); doT = true;
          } break;
          case 2: {
            bf16 o = (bf16)(v - auxf[(long)r*g.ldax + c]);
            Cb[co] = o; tv[reg] = o; doT = true;
          } break;
          case 3: {
            float v3 = silu_bwd_f((float)auxb[(long)r*g.ldax + c]) * v * rowv[r];
            tv[reg]  = (bf16)v3;
            tv2[reg] = (bf16)(v3 * rowv2[r]);
            doT = true; doT2 = true;
          } break;
          case 10: {
            Cf[co] = v + auxf[(long)r*g.ldax + c]*clv;
          } break;
          case 11: {
            float o = v + g.bqkv[c];
            if (c < 256)      g.Q [(long)r*256 + c]       = (bf16)o;
            else if (c < 512) { g.Ko[(long)r*256 + (c-256)] = (bf16)o; tv[reg] = (bf16)o; doT = true; }
            else              g.Vo[(long)r*256 + (c-512)] = o;
          } break;
        }
      }
      if (hasT && doT) {
        bf16x4 t4 = { tv[0], tv[1], tv[2], tv[3] };
        *(bf16x4*)&sh[cloc*72 + rloc] = t4;
        if (doT2) {
          bf16x4 t4b = { tv2[0], tv2[1], tv2[2], tv2[3] };
          *(bf16x4*)&sh[64*72 + cloc*72 + rloc] = t4b;
        }
      }
    }
  }

  // coalesced transposed write-back through LDS (TM=64 tiles only)
  if (hasT) {
    __syncthreads();
    const int cl = tid >> 2, rl = (tid & 3)*16;
    bf16x8 u0 = *(const bf16x8*)&sh[cl*72 + rl];
    bf16x8 u1 = *(const bf16x8*)&sh[cl*72 + rl + 8];
    bf16* d;
    if (mode == 11) {
      // Kt[b][c-256][l]; row0 is 64-aligned and never crosses a batch boundary (64 | 2048)
      const int b = row0 >> 11, l0r = row0 & 2047;
      d = Ct + (long)b*g.sCt + (long)(col0-256+cl)*g.ldct + l0r + rl;
    } else {
      d = Ct + (long)(col0+cl)*g.ldct + row0 + rl;
    }
    *(bf16x8*)d       = u0;
    *(bf16x8*)(d + 8) = u1;
    if (mode == 3) {
      bf16x8 v0 = *(const bf16x8*)&sh[64*72 + cl*72 + rl];
      bf16x8 v1 = *(const bf16x8*)&sh[64*72 + cl*72 + rl + 8];
      bf16* d2 = Ct2 + (long)(col0+cl)*g.ldct + row0 + rl;
      *(bf16x8*)d2       = v0;
      *(bf16x8*)(d2 + 8) = v1;
    }
  }
}

__global__ __launch_bounds__(256)
void mfma_gemm64(MArgs g){ gemm_body<64>(g, blockIdx.x, blockIdx.y, blockIdx.z); }

// dual-job W-next (TM=64): z<4 -> g1 (batch z), z>=4 -> g2 (batch z-4)
__global__ __launch_bounds__(256)
void wnext_gemm(MArgs g1, MArgs g2){
  const int z = blockIdx.z;
  const MArgs& g = (z < 4) ? g1 : g2;
  const int bz = z & 3;
  if ((int)blockIdx.x*64 >= g.M || (int)blockIdx.y*64 >= g.N) return;
  gemm_body<64>(g, blockIdx.x, blockIdx.y, bz);
}

// ===================== banded P producer (64m x 128l tiles), depth-2 + dbuf =====================
// P[m,l] = -(A[m].B1[l]) * exp(cd[m]-cd[l]) * (l<=m) * (ISLR? lr[l]:1)
struct PArgs {
  const bf16 *A, *B1;
  long sA, sB1;
  const double* cd; long sCd;
  const float* lrv; long sLr;
  bf16* P;
};

template<int KS64, int ISLR>
__global__ __launch_bounds__(256)
void pgen(PArgs g)
{
  const int mt = blockIdx.x, slot = blockIdx.y, bz = blockIdx.z;
  const int m0 = mt*64;
  const int l0 = (m0 & ~127) - slot*128;
  if (l0 < 0) return;
  const double* cd = g.cd + (long)bz*g.sCd;
  const int lref = (l0+127 < m0) ? (l0+127) : m0;
  if (cd[m0] - cd[lref] < CUTOFF) return;

  const int K1 = KS64*64;
  const bf16* A  = g.A  + (long)bz*g.sA;
  const bf16* B1 = g.B1 + (long)bz*g.sB1;
  const float* lrv = ISLR ? (g.lrv + (long)bz*g.sLr) : (const float*)0;

  const int tid = threadIdx.x;
  const int lane = tid & 63, w = tid >> 6;
  const int wr = (w>>1)*32, wc = (w&1)*64;
  const int l15 = lane & 15, quad = lane >> 4;
  const int rowA = tid >> 2, kA = (tid & 3) * 16;
  const int rowB = tid >> 1, kB = (tid & 1) * 32;

  constexpr int BUFP = (64+128)*SB;
  __shared__ __align__(16) bf16 sh[2*BUFP];

  f32x4 O[2][4];
  #pragma unroll
  for (int i=0;i<2;i++)
    #pragma unroll
    for (int j=0;j<4;j++)
      #pragma unroll
      for (int r=0;r<4;r++) O[i][j][r] = 0.f;

  const bf16* Abase = A + (long)(m0+rowA)*K1 + kA;
  const bf16* Bbase = B1 + (long)(l0+rowB)*K1 + kB;

  bf16x8 paA0, paA1, pbA[4], paB0, paB1, pbB[4];
  paA0 = *(const bf16x8*)Abase;
  paA1 = *(const bf16x8*)(Abase + 8);
  #pragma unroll
  for (int p=0;p<4;p++) pbA[p] = *(const bf16x8*)(Bbase + p*8);
  paB0 = *(const bf16x8*)(Abase + 64);
  paB1 = *(const bf16x8*)(Abase + 64 + 8);
  #pragma unroll
  for (int p=0;p<4;p++) pbB[p] = *(const bf16x8*)(Bbase + 64 + p*8);

  auto compute = [&](const bf16* As, const bf16* Bs){
    #pragma unroll
    for (int ch=0; ch<2; ch++){
      bf16x8 af[2], bfr[4];
      #pragma unroll
      for (int i=0;i<2;i++) af[i]  = *(const bf16x8*)&As[(wr + i*16 + l15)*SB + ch*32 + quad*8];
      #pragma unroll
      for (int j=0;j<4;j++) bfr[j] = *(const bf16x8*)&Bs[(wc + j*16 + l15)*SB + ch*32 + quad*8];
      #pragma unroll
      for (int i=0;i<2;i++)
        #pragma unroll
        for (int j=0;j<4;j++)
          O[i][j] = __builtin_amdgcn_mfma_f32_16x16x32_bf16(af[i], bfr[j], O[i][j], 0, 0, 0);
    }
  };

  // KS64 is even (4 or 8): process steps in pairs
  for (int ks=0; ks<KS64; ks+=2){
    {  // even step: buffer 0, set A
      bf16* As = sh; bf16* Bs = sh + 64*SB;
      *(bf16x8*)&As[rowA*SB + kA]     = paA0;
      *(bf16x8*)&As[rowA*SB + kA + 8] = paA1;
      #pragma unroll
      for (int p=0;p<4;p++) *(bf16x8*)&Bs[rowB*SB + kB + p*8] = pbA[p];
      __syncthreads();
      if (ks+2 < KS64) {
        const int kn = (ks+2)*64;
        paA0 = *(const bf16x8*)(Abase + kn);
        paA1 = *(const bf16x8*)(Abase + kn + 8);
        #pragma unroll
        for (int p=0;p<4;p++) pbA[p] = *(const bf16x8*)(Bbase + kn + p*8);
      }
      compute(As, Bs);
    }
    {  // odd step: buffer 1, set B
      bf16* As = sh + BUFP; bf16* Bs = sh + BUFP + 64*SB;
      *(bf16x8*)&As[rowA*SB + kA]     = paB0;
      *(bf16x8*)&As[rowA*SB + kA + 8] = paB1;
      #pragma unroll
      for (int p=0;p<4;p++) *(bf16x8*)&Bs[rowB*SB + kB + p*8] = pbB[p];
      __syncthreads();
      if (ks+3 < KS64) {
        const int kn = (ks+3)*64;
        paB0 = *(const bf16x8*)(Abase + kn);
        paB1 = *(const bf16x8*)(Abase + kn + 8);
        #pragma unroll
        for (int p=0;p<4;p++) pbB[p] = *(const bf16x8*)(Bbase + kn + p*8);
      }
      compute(As, Bs);
    }
  }

  bf16* Pt = g.P + (((long)bz*32 + mt)*3 + slot) * (64*128);
  float cl[4], lv[4];
  #pragma unroll
  for (int j=0;j<4;j++){
    const int l = l0 + wc + j*16 + l15;
    cl[j] = (float)cd[l];
    if (ISLR) lv[j] = lrv[l];
  }
  #pragma unroll
  for (int i=0;i<2;i++)
    #pragma unroll
    for (int reg=0; reg<4; reg++){
      const int mloc = wr + i*16 + quad*4 + reg;
      const int m = m0 + mloc;
      const float cm = (float)cd[m];
      #pragma unroll
      for (int j=0;j<4;j++){
        const int lloc = wc + j*16 + l15;
        const int l = l0 + lloc;
        float v = -O[i][j][reg] * __expf(cm - cl[j]);
        if (ISLR) v *= lv[j];
        if (l > m) v = 0.f;
        Pt[mloc*128 + lloc] = (bf16)v;
      }
    }
}

// ===================== consumer: O = wdc[m]*(A.W^T) + sum_slots P.B2, depth-2 + dbuf ====
// 64m x 64n tiles. ZSPLIT: half0 = cross term, half1 = band term, fp32 atomic into Cf.
struct CArgs {
  const bf16 *A, *W, *P, *B2;
  long sA, sW, sB2;
  int ldb2;
  const double* cd; long sCd;
  const float* wdc; long sWdc;
  float* Cf; long sCf;
  bf16* Cb; long sCb;
  int ldc;
};

template<int KS64, int SILU, int ZSPLIT>
__global__ __launch_bounds__(256)
void cons(CArgs g)
{
  const int mt = blockIdx.x;
  const int m0 = mt*64, n0 = blockIdx.y*64;
  const int bz   = ZSPLIT ? (blockIdx.z >> 1) : blockIdx.z;
  const int half = ZSPLIT ? (blockIdx.z & 1)  : 0;
  const int K1 = KS64*64;
  const bf16* A  = g.A  + (long)bz*g.sA;
  const bf16* W  = g.W  + (long)bz*g.sW;
  const bf16* B2 = g.B2 + (long)bz*g.sB2;
  const double* cd = g.cd + (long)bz*g.sCd;
  const float* wdc = g.wdc + (long)bz*g.sWdc;

  const int tid = threadIdx.x;
  const int lane = tid & 63, w = tid >> 6;
  const int wr = (w>>1)*32, wc = (w&1)*32;
  const int l15 = lane & 15, quad = lane >> 4;
  const int rowA = tid >> 2, kA = (tid & 3) * 16;

  bool alive[3];
  int nalive = 0;
  #pragma unroll
  for (int s=0;s<3;s++){
    const int l0 = (m0 & ~127) - s*128;
    bool a = (l0 >= 0);
    if (a) {
      const int lref = (l0+127 < m0) ? (l0+127) : m0;
      a = (cd[m0] - cd[lref] >= CUTOFF);
    }
    alive[s] = a; nalive += a ? 1 : 0;
  }
  if (ZSPLIT && half == 1 && nalive == 0) return;

  constexpr int BUFC = 128*SB;
  __shared__ __align__(16) bf16 sh[2*BUFC];

  f32x4 O[2][2];
  #pragma unroll
  for (int i=0;i<2;i++)
    #pragma unroll
    for (int j=0;j<2;j++)
      #pragma unroll
      for (int r=0;r<4;r++) O[i][j][r] = 0.f;

  auto compute = [&](const bf16* As, const bf16* Bs){
    #pragma unroll
    for (int ch=0; ch<2; ch++){
      bf16x8 af[2], bfr[2];
      #pragma unroll
      for (int i=0;i<2;i++) af[i]  = *(const bf16x8*)&As[(wr + i*16 + l15)*SB + ch*32 + quad*8];
      #pragma unroll
      for (int j=0;j<2;j++) bfr[j] = *(const bf16x8*)&Bs[(wc + j*16 + l15)*SB + ch*32 + quad*8];
      #pragma unroll
      for (int i=0;i<2;i++)
        #pragma unroll
        for (int j=0;j<2;j++)
          O[i][j] = __builtin_amdgcn_mfma_f32_16x16x32_bf16(af[i], bfr[j], O[i][j], 0, 0, 0);
    }
  };

  // ---- cross phase: O = A . W^T, scaled by wdc[m] (KS64 even: pairs)
  if (half == 0) {
    const bf16* Abase = A + (long)(m0+rowA)*K1 + kA;
    const bf16* Wbase = W + (long)(n0+rowA)*K1 + kA;
    bf16x8 aA0,aA1,wA0,wA1, aB0,aB1,wB0,wB1;
    aA0 = *(const bf16x8*)Abase;        aA1 = *(const bf16x8*)(Abase + 8);
    wA0 = *(const bf16x8*)Wbase;        wA1 = *(const bf16x8*)(Wbase + 8);
    aB0 = *(const bf16x8*)(Abase + 64); aB1 = *(const bf16x8*)(Abase + 72);
    wB0 = *(const bf16x8*)(Wbase + 64); wB1 = *(const bf16x8*)(Wbase + 72);
    for (int ks=0; ks<KS64; ks+=2){
      {  // even: buffer 0, set A
        bf16* As = sh; bf16* Bs = sh + 64*SB;
        *(bf16x8*)&As[rowA*SB + kA]     = aA0;
        *(bf16x8*)&As[rowA*SB + kA + 8] = aA1;
        *(bf16x8*)&Bs[rowA*SB + kA]     = wA0;
        *(bf16x8*)&Bs[rowA*SB + kA + 8] = wA1;
        __syncthreads();
        if (ks+2 < KS64) {
          const int kn = (ks+2)*64;
          aA0 = *(const bf16x8*)(Abase + kn); aA1 = *(const bf16x8*)(Abase + kn + 8);
          wA0 = *(const bf16x8*)(Wbase + kn); wA1 = *(const bf16x8*)(Wbase + kn + 8);
        }
        compute(As, Bs);
      }
      {  // odd: buffer 1, set B
        bf16* As = sh + BUFC; bf16* Bs = sh + BUFC + 64*SB;
        *(bf16x8*)&As[rowA*SB + kA]     = aB0;
        *(bf16x8*)&As[rowA*SB + kA + 8] = aB1;
        *(bf16x8*)&Bs[rowA*SB + kA]     = wB0;
        *(bf16x8*)&Bs[rowA*SB + kA + 8] = wB1;
        __syncthreads();
        if (ks+3 < KS64) {
          const int kn = (ks+3)*64;
          aB0 = *(const bf16x8*)(Abase + kn); aB1 = *(const bf16x8*)(Abase + kn + 8);
          wB0 = *(const bf16x8*)(Wbase + kn); wB1 = *(const bf16x8*)(Wbase + kn + 8);
        }
        compute(As, Bs);
      }
    }
    #pragma unroll
    for (int i=0;i<2;i++)
      #pragma unroll
      for (int reg=0; reg<4; reg++){
        const float s = wdc[m0 + wr + i*16 + quad*4 + reg];
        #pragma unroll
        for (int j=0;j<2;j++) O[i][j][reg] *= s;
      }
  }

  // ---- band phase: O += P . B2  (flat step list over alive slots, depth-2)
  if (!ZSPLIT || half == 1) {
    int s0a=0, s1a=0, s2a=0, na=0;
    #pragma unroll
    for (int s=0;s<3;s++) if (alive[s]) { if (na==0) s0a=s; else if (na==1) s1a=s; else s2a=s; na++; }
    const int nst = na*2;   // always even
    if (nst > 0) {
      auto Pptr = [&](int t)->const bf16* {
        const int i = t>>1;
        const int s = (i==0) ? s0a : ((i==1) ? s1a : s2a);
        return g.P + (((long)bz*32 + mt)*3 + s)*(64*128) + (long)rowA*128 + (t&1)*64 + kA;
      };
      auto Bptr = [&](int t)->const bf16* {
        const int i = t>>1;
        const int s = (i==0) ? s0a : ((i==1) ? s1a : s2a);
        const int l0 = (m0 & ~127) - s*128;
        return B2 + (long)(n0+rowA)*g.ldb2 + l0 + (t&1)*64 + kA;
      };
      bf16x8 pA0,pA1,bA0,bA1, pB0,pB1,bB0,bB1;
      { const bf16* pp = Pptr(0); pA0 = *(const bf16x8*)pp; pA1 = *(const bf16x8*)(pp+8);
        const bf16* bb = Bptr(0); bA0 = *(const bf16x8*)bb; bA1 = *(const bf16x8*)(bb+8); }
      { const bf16* pp = Pptr(1); pB0 = *(const bf16x8*)pp; pB1 = *(const bf16x8*)(pp+8);
        const bf16* bb = Bptr(1); bB0 = *(const bf16x8*)bb; bB1 = *(const bf16x8*)(bb+8); }
      for (int t=0; t<nst; t+=2){
        {  // even step: buffer 0, set A
          bf16* As = sh; bf16* Bs = sh + 64*SB;
          *(bf16x8*)&As[rowA*SB + kA]     = pA0;
          *(bf16x8*)&As[rowA*SB + kA + 8] = pA1;
          *(bf16x8*)&Bs[rowA*SB + kA]     = bA0;
          *(bf16x8*)&Bs[rowA*SB + kA + 8] = bA1;
          __syncthreads();
          if (t+2 < nst) {
            const bf16* pp = Pptr(t+2); pA0 = *(const bf16x8*)pp; pA1 = *(const bf16x8*)(pp+8);
            const bf16* bb = Bptr(t+2); bA0 = *(const bf16x8*)bb; bA1 = *(const bf16x8*)(bb+8);
          }
          compute(As, Bs);
        }
        {  // odd step: buffer 1, set B
          bf16* As = sh + BUFC; bf16* Bs = sh + BUFC + 64*SB;
          *(bf16x8*)&As[rowA*SB + kA]     = pB0;
          *(bf16x8*)&As[rowA*SB + kA + 8] = pB1;
          *(bf16x8*)&Bs[rowA*SB + kA]     = bB0;
          *(bf16x8*)&Bs[rowA*SB + kA + 8] = bB1;
          __syncthreads();
          if (t+3 < nst) {
            const bf16* pp = Pptr(t+3); pB0 = *(const bf16x8*)pp; pB1 = *(const bf16x8*)(pp+8);
            const bf16* bb = Bptr(t+3); bB0 = *(const bf16x8*)bb; bB1 = *(const bf16x8*)(bb+8);
          }
          compute(As, Bs);
        }
      }
    }
  }

  // ---- epilogue
  #pragma unroll
  for (int i=0;i<2;i++){
    const int rb = m0 + wr + i*16 + quad*4;
    #pragma unroll
    for (int j=0;j<2;j++){
      const int c = n0 + wc + j*16 + l15;
      #pragma unroll
      for (int reg=0; reg<4; reg++){
        const long co = (long)(rb+reg)*g.ldc + c;
        if (ZSPLIT)     unsafeAtomicAdd(&g.Cf[(long)bz*g.sCf + co], O[i][j][reg]);
        else if (SILU)  g.Cb[(long)bz*g.sCb + co] = (bf16)silu_f(O[i][j][reg]);
        else            g.Cf[(long)bz*g.sCf + co] = O[i][j][reg];
      }
    }
  }
}

// ===================== front matter: 1D job ladder =====================
// [0,1024)   conv x -> xb
// [1024,1280) conv W1 -> W1b
// [1280,1536) conv W2 -> W2b
// [1536,2560) zero out0
// [2560,2608) transpose Wq/Wk/Wv -> Wqkvt
// [2608,2736) transpose W2 -> W2t
// [2736,4784) scalar_proj (4 rows/block)
struct FrontArgs {
  const float *x, *W1, *W2, *Wq, *Wk, *Wv;
  bf16 *xb, *W1b, *W2b, *Wqkvt, *W2t;
  float* out0;
  const float *wlr, *blr, *wwd, *bwd, *lbl, *lbw;
  float *lr, *lw;
  long LD4, HD4, HD;
};

__global__ __launch_bounds__(256)
void front_kernel(FrontArgs f)
{
  __shared__ bf16 t[64][72];
  const int bid = blockIdx.x;
  const int tid = threadIdx.x;

  if (bid < 1536) {
    const float* src; bf16* dst; long n; long base;
    if (bid < 1024)      { src = f.x;  dst = f.xb;  n = f.LD4; base = (long)bid*2048; }
    else if (bid < 1280) { src = f.W1; dst = f.W1b; n = f.HD4; base = (long)(bid-1024)*2048; }
    else                 { src = f.W2; dst = f.W2b; n = f.HD4; base = (long)(bid-1280)*2048; }
    long i = base + (long)tid*8;
    if (i >= n) return;
    float4 a = *(const float4*)&src[i];
    float4 b = *(const float4*)&src[i+4];
    bf16x8 o;
    o[0]=(bf16)a.x; o[1]=(bf16)a.y; o[2]=(bf16)a.z; o[3]=(bf16)a.w;
    o[4]=(bf16)b.x; o[5]=(bf16)b.y; o[6]=(bf16)b.z; o[7]=(bf16)b.w;
    *(bf16x8*)&dst[i] = o;
    return;
  }
  if (bid < 2560) {
    long i = (long)(bid-1536)*2048 + (long)tid*8;
    float4 z = {0.f,0.f,0.f,0.f};
    *(float4*)&f.out0[i]   = z;
    *(float4*)&f.out0[i+4] = z;
    return;
  }
  if (bid < 2736) {
    const float* ip; bf16* op; int R, C; int r0, c0;
    if (bid < 2608) {
      const int r = bid - 2560;
      const int z = r >> 4, rem = r & 15;
      ip = z==0 ? f.Wq : (z==1 ? f.Wk : f.Wv);
      op = f.Wqkvt + (long)z*256*256;
      R = 256; C = 256;
      r0 = (rem & 3)*64; c0 = (rem >> 2)*64;
    } else {
      const int r = bid - 2608;
      const int b = r >> 5, rem = r & 31;
      ip = f.W2 + (long)b*f.HD;
      op = f.W2t + (long)b*f.HD;
      R = 256; C = 512;
      r0 = (rem & 3)*64; c0 = (rem >> 2)*64;
    }
    const int lr_ = tid>>2, lc = (tid&3)*16;
    #pragma unroll
    for (int q=0;q<4;q++){
      float4 a = *(const float4*)&ip[(long)(r0+lr_)*C + c0+lc + q*4];
      t[lr_][lc+q*4+0] = (bf16)a.x; t[lr_][lc+q*4+1] = (bf16)a.y;
      t[lr_][lc+q*4+2] = (bf16)a.z; t[lr_][lc+q*4+3] = (bf16)a.w;
    }
    __syncthreads();
    const int oc = tid>>2, orr = (tid&3)*16;
    bf16x8 u, v;
    #pragma unroll
    for (int i=0;i<8;i++){ u[i] = t[orr+i][oc]; v[i] = t[orr+8+i][oc]; }
    *(bf16x8*)&op[(long)(c0+oc)*R + r0+orr]   = u;
    *(bf16x8*)&op[(long)(c0+oc)*R + r0+orr+8] = v;
    return;
  }
  {
    const int row  = (bid-2736)*4 + (tid >> 6);
    const int lane = tid & 63;
    const float4 a = ((const float4*)(f.x + (long)row*256))[lane];
    const float4 u = ((const float4*)f.wlr)[lane];
    const float4 w = ((const float4*)f.wwd)[lane];
    float d1 = a.x*u.x + a.y*u.y + a.z*u.z + a.w*u.w;
    float d2 = a.x*w.x + a.y*w.y + a.z*w.z + a.w*w.w;
    #pragma unroll
    for (int off=32; off; off>>=1) {
      d1 += __shfl_down(d1, off);
      d2 += __shfl_down(d2, off);
    }
    if (lane == 0) {
      float s1 = 1.f/(1.f+expf(-(d1 + f.blr[0])));
      f.lr[row] = expf(f.lbl[0]) * s1;
      float s2 = 1.f/(1.f+expf(-(d2 + f.bwd[0])));
      f.lw[row] = logf(1.f - expf(f.lbw[0]) * s2);
    }
  }
}

// blocks 0..3: per-batch fp64 scan + derived; block 4: bias concat
__global__ __launch_bounds__(256)
void cumsum_kernel(const float* __restrict__ lw, const float* __restrict__ lr,
                   double* __restrict__ cd, float* __restrict__ wdc,
                   float* __restrict__ se1, float* __restrict__ se2, int L,
                   const float* __restrict__ bq, const float* __restrict__ bk,
                   const float* __restrict__ bv, float* __restrict__ bqkv)
{
  const int b = blockIdx.x;
  const int t = threadIdx.x;
  if (b == 4) {
    for (int i = t; i < 768; i += 256)
      bqkv[i] = (i<256) ? bq[i] : ((i<512) ? bk[i-256] : bv[i-512]);
    return;
  }
  const float* lwb = lw + (long)b*L;
  __shared__ double sum_s[256];
  double loc[8];
  double s = 0.0;
  #pragma unroll
  for (int i=0;i<8;i++){ s += (double)lwb[t*8+i]; loc[i] = s; }
  sum_s[t] = s;
  __syncthreads();
  for (int off=1; off<256; off<<=1){
    double v = 0.0;
    if (t >= off) v = sum_s[t-off];
    __syncthreads();
    sum_s[t] += v;
    __syncthreads();
  }
  const double prefix = (t > 0) ? sum_s[t-1] : 0.0;
  const double total  = sum_s[255];
  #pragma unroll
  for (int i=0;i<8;i++){
    double c = prefix + loc[i];
    long idx = (long)b*L + t*8 + i;
    cd[idx]  = c;
    wdc[idx] = (float)exp(c);
    double e = exp(total - c);
    se1[idx] = (float)(-e);
    se2[idx] = (float)(-e) * lr[idx];
  }
}

extern "C" void kernel_launch(void* const* d_in, const int* in_sizes, int n_in,
                              void* d_out, int out_size, void* d_ws, size_t ws_size,
                              hipStream_t stream)
{
  const int Bn = 4, L = 2048, D = 256, H = 512;
  const long LD = (long)L*D, LH = (long)L*H, HD = (long)H*D;

  const float* x   = (const float*)d_in[0];
  const float* W1  = (const float*)d_in[1];
  const float* W2  = (const float*)d_in[2];
  const float* Wq  = (const float*)d_in[3];
  const float* bq  = (const float*)d_in[4];
  const float* Wk  = (const float*)d_in[5];
  const float* bk  = (const float*)d_in[6];
  const float* Wv  = (const float*)d_in[7];
  const float* bv  = (const float*)d_in[8];
  const float* wlr = (const float*)d_in[9];
  const float* blr = (const float*)d_in[10];
  const float* wwd = (const float*)d_in[11];
  const float* bwd = (const float*)d_in[12];
  const float* lbl = (const float*)d_in[13];
  const float* lbw = (const float*)d_in[14];
  (void)in_sizes; (void)n_in; (void)out_size; (void)ws_size;

  float* out0 = (float*)d_out;            // Z2_      [B,L,D]
  float* out1 = out0 + (long)Bn*LD;       // W1_next  [B,H,D]
  float* out2 = out1 + (long)Bn*HD;       // W2_next  [B,D,H]

  char* wsp = (char*)d_ws;
  size_t off = 0;
  auto alloc = [&](size_t bytes)->void*{
    void* p = wsp + off; off += (bytes + 255) & ~(size_t)255; return p;
  };
  bf16* xb    = (bf16*)alloc((size_t)Bn*LD*2);
  bf16* Wqkvt = (bf16*)alloc((size_t)3*D*D*2);
  float* bqkv = (float*)alloc((size_t)3*D*4);
  bf16* W1b  = (bf16*)alloc((size_t)Bn*HD*2);
  bf16* W2b  = (bf16*)alloc((size_t)Bn*HD*2);
  bf16* W2t  = (bf16*)alloc((size_t)Bn*HD*2);
  bf16* Qb   = (bf16*)alloc((size_t)Bn*LD*2);
  bf16* Kb   = (bf16*)alloc((size_t)Bn*LD*2);
  bf16* Kt   = (bf16*)alloc((size_t)Bn*LD*2);
  float* Vf  = (float*)alloc((size_t)Bn*LD*4);
  bf16* Z1b  = (bf16*)alloc((size_t)Bn*LH*2);
  bf16* X2b  = (bf16*)alloc((size_t)Bn*LH*2);
  bf16* X2t  = (bf16*)alloc((size_t)Bn*LH*2);   // pre-scaled by se2 (only used by W2_next)
  bf16* gZb  = (bf16*)alloc((size_t)Bn*LD*2);
  bf16* gZt  = (bf16*)alloc((size_t)Bn*LD*2);
  bf16* A1t  = (bf16*)alloc((size_t)Bn*LH*2);
  bf16* A1s  = (bf16*)alloc((size_t)Bn*LH*2);   // A1t pre-scaled by se1 (only used by W1_next)
  bf16* X2_b = (bf16*)alloc((size_t)Bn*LH*2);
  bf16* Pb1  = (bf16*)alloc((size_t)Bn*32*3*64*128*2);
  bf16* Pb2  = (bf16*)alloc((size_t)Bn*32*3*64*128*2);
  float* lrb = (float*)alloc((size_t)Bn*L*4);
  float* lwb = (float*)alloc((size_t)Bn*L*4);
  float* wdc = (float*)alloc((size_t)Bn*L*4);
  float* se1 = (float*)alloc((size_t)Bn*L*4);
  float* se2 = (float*)alloc((size_t)Bn*L*4);
  double* cdb = (double*)alloc((size_t)Bn*L*8);

  auto run64 = [&](const MArgs& g, int Z){
    dim3 grid(g.M/64, g.N/64, Z);
    mfma_gemm64<<<grid, 256, 0, stream>>>(g);
  };

  // ---- 1. front matter (conv + transposes + scalar_proj + out0 zero)
  {
    FrontArgs f{};
    f.x = x; f.W1 = W1; f.W2 = W2; f.Wq = Wq; f.Wk = Wk; f.Wv = Wv;
    f.xb = xb; f.W1b = W1b; f.W2b = W2b; f.Wqkvt = Wqkvt; f.W2t = W2t;
    f.out0 = out0;
    f.wlr = wlr; f.blr = blr; f.wwd = wwd; f.bwd = bwd; f.lbl = lbl; f.lbw = lbw;
    f.lr = lrb; f.lw = lwb;
    f.LD4 = Bn*LD; f.HD4 = Bn*HD; f.HD = HD;
    front_kernel<<<dim3(4784), 256, 0, stream>>>(f);
  }
  // ---- 2. cumsum + bias concat
  cumsum_kernel<<<dim3(5), 256, 0, stream>>>(lwb, lrb, cdb, wdc, se1, se2, L, bq, bk, bv, bqkv);

  // ---- 3. fused QKV (M = B*L, N = 768), TM=64 for 4 blocks/CU; Kt via LDS-coalesced Ct
  {
    MArgs g{}; g.A = xb; g.lda = D; g.B = Wqkvt; g.ldb = D;
    g.M = Bn*L; g.N = 3*D; g.K = D; g.mode = 11; g.ldc = 0;
    g.Q = Qb; g.Ko = Kb; g.Vo = Vf; g.bqkv = bqkv;
    g.Ct = Kt; g.sCt = LD; g.ldct = L;
    mfma_gemm64<<<dim3(128, 12, 1), 256, 0, stream>>>(g);
  }
  // ---- 4. Z1 = K.W1^T ; Cb=Z1, Cb2=silu, Ct=(silu*se2)^T
  {
    MArgs g{}; g.A = Kb; g.lda = D; g.sA = LD; g.B = W1b; g.ldb = D; g.sB = HD;
    g.M = L; g.N = H; g.K = D; g.mode = 1; g.ldc = H;
    g.Cb = Z1b; g.sCb = LH; g.Cb2 = X2b; g.sCb2 = LH;
    g.Ct = X2t; g.sCt = LH; g.ldct = L;
    g.rowv = se2; g.sRowv = L;
    run64(g, Bn);
  }
  // ---- 5. gZ2 = X2.W2^T - V; gZt via Ct
  {
    MArgs g{}; g.A = X2b; g.lda = H; g.sA = LH; g.B = W2b; g.ldb = H; g.sB = HD;
    g.M = L; g.N = D; g.K = H; g.mode = 2; g.ldc = D;
    g.auxf = Vf; g.ldax = D; g.sAuxf = LD; g.Cb = gZb; g.sCb = LD;
    g.Ct = gZt; g.sCt = LD; g.ldct = L; run64(g, Bn);
  }
  // ---- 6. A1 = silu_bwd(Z1)*(gZ2.W2)*lr; Ct=A1t, Ct2=A1t*se1
  {
    MArgs g{}; g.A = gZb; g.lda = D; g.sA = LD; g.B = W2t; g.ldb = D; g.sB = HD;
    g.M = L; g.N = H; g.K = D; g.mode = 3; g.ldc = H;
    g.auxb = Z1b; g.ldax = H; g.sAuxb = LH;
    g.rowv = lrb; g.sRowv = L; g.rowv2 = se1; g.sRowv2 = L;
    g.Ct = A1t; g.sCt = LH; g.ldct = L;
    g.Ct2 = A1s; g.sCt2 = LH;
    run64(g, Bn);
  }
  // ---- 7. P1 banded tiles
  {
    PArgs p{};
    p.A = Qb; p.sA = LD; p.B1 = Kb; p.sB1 = LD;
    p.cd = cdb; p.sCd = L; p.P = Pb1;
    pgen<4,0><<<dim3(32,3,Bn), 256, 0, stream>>>(p);
  }
  // ---- 8. cons1: X2_ = silu( wdc[m]*(Q.W1^T) + sum P1.A1t )
  {
    CArgs c{};
    c.A = Qb; c.sA = LD; c.W = W1b; c.sW = HD;
    c.P = Pb1; c.B2 = A1t; c.sB2 = LH; c.ldb2 = L;
    c.cd = cdb; c.sCd = L; c.wdc = wdc; c.sWdc = L;
    c.Cb = X2_b; c.sCb = LH; c.ldc = H;
    cons<4,1,0><<<dim3(32, H/64, Bn), 256, 0, stream>>>(c);
  }
  // ---- 9. P2 banded tiles
  {
    PArgs p{};
    p.A = X2_b; p.sA = LH; p.B1 = X2b; p.sB1 = LH;
    p.cd = cdb; p.sCd = L; p.lrv = lrb; p.sLr = L; p.P = Pb2;
    pgen<8,1><<<dim3(32,3,Bn), 256, 0, stream>>>(p);
  }
  // ---- 10. cons2: out0 += wdc[m]*(X2_.W2^T) + sum P2.gZt   (z-split, atomic)
  {
    CArgs c{};
    c.A = X2_b; c.sA = LH; c.W = W2b; c.sW = HD;
    c.P = Pb2; c.B2 = gZt; c.sB2 = LD; c.ldb2 = L;
    c.cd = cdb; c.sCd = L; c.wdc = wdc; c.sWdc = L;
    c.Cf = out0; c.sCf = LD; c.ldc = D;
    cons<8,0,1><<<dim3(32, D/64, Bn*2), 256, 0, stream>>>(c);
  }
  // ---- 11. W1_next + W2_next in one launch (TM=64; inputs pre-scaled; ballot dead-scan)
  {
    MArgs g1{}; g1.A = A1s; g1.lda = L; g1.sA = LH; g1.B = Kt; g1.ldb = L; g1.sB = LD;
    g1.M = H; g1.N = D; g1.K = L; g1.mode = 10; g1.ldc = D;
    g1.cd = cdb; g1.sCd = L;
    g1.auxf = W1; g1.ldax = D; g1.sAuxf = HD; g1.clp = wdc + (L-1); g1.sClp = L;
    g1.Cf = out1; g1.sCf = HD;

    MArgs g2{}; g2.A = gZt; g2.lda = L; g2.sA = LD; g2.B = X2t; g2.ldb = L; g2.sB = LH;
    g2.M = D; g2.N = H; g2.K = L; g2.mode = 10; g2.ldc = H;
    g2.cd = cdb; g2.sCd = L;
    g2.auxf = W2; g2.ldax = H; g2.sAuxf = HD; g2.clp = wdc + (L-1); g2.sClp = L;
    g2.Cf = out2; g2.sCf = HD;

    wnext_gemm<<<dim3(8,8,8), 256, 0, stream>>>(g1, g2);
  }
}